// Round 1
// baseline (103.717 us; speedup 1.0000x reference)
//
#include <hip/hip_runtime.h>

// Weighted 2D Procrustes (Kabsch) with z-padding == closed-form 2x2 polar factor.
// B=1024 batches, N=4096 points. Output: R [B,3,3] then t [B,3,1], fp32.
//
// R6: geometry change vs R5 (102.8 us). Timed graph = 2 harness workspace
// fills (~84 us, untouchable) + kernel (~19 us). Kernel was at 4.2 TB/s
// (66% of achievable) with 256 thr/block -> only 16 waves/CU and ~120 VGPR
// (20 hoisted float4 + 9 f64 acc). R6 uses 512 thr/block, 2 passes/thread:
// 10 hoisted float4 (40 VGPR) + 9 f64 acc -> ~70 VGPR, ~24-28 waves/CU.
// More resident waves streaming loads; per-block serial tail amortized.
//
// Moments + det-sign decision stay in fp64: det(A) ties within fp32
// accumulation noise occur for ~1/1024 random batches and flipped the Rzz
// branch across graph replays in R1. Fixed-order fp64 summation (order is
// still fixed here, just re-chunked) is replay-invariant.

constexpr int BATCH = 1024;
constexpr int NPTS  = 4096;
constexpr int TPB   = 512;             // 8 waves/block
constexpr int PASSES = NPTS / (TPB * 4); // = 2
constexpr double EPSV = 1e-4;

__device__ __forceinline__ double wredd(double v) {
    #pragma unroll
    for (int off = 1; off < 64; off <<= 1) v += __shfl_xor(v, off, 64);
    return v;
}

__global__ __launch_bounds__(TPB) void procrustes_kernel(
    const float* __restrict__ src, const float* __restrict__ tgt,
    const float* __restrict__ wts, float* __restrict__ out)
{
    const int b   = blockIdx.x;
    const int tid = threadIdx.x;
    const float* sb = src + (size_t)b * (NPTS * 2);
    const float* tb = tgt + (size_t)b * (NPTS * 2);
    const float* wb = wts + (size_t)b * NPTS;

    // ---- issue ALL loads first (10 x float4 = 160 B/thread, coalesced) ----
    float4 wv[PASSES], s0[PASSES], s1[PASSES], t0[PASSES], t1[PASSES];
    #pragma unroll
    for (int pass = 0; pass < PASSES; ++pass) {
        const int i = tid * 4 + pass * (TPB * 4);
        wv[pass] = *reinterpret_cast<const float4*>(wb + i);
        s0[pass] = *reinterpret_cast<const float4*>(sb + 2 * i);
        s1[pass] = *reinterpret_cast<const float4*>(sb + 2 * i + 4);
        t0[pass] = *reinterpret_cast<const float4*>(tb + 2 * i);
        t1[pass] = *reinterpret_cast<const float4*>(tb + 2 * i + 4);
    }

    // acc: 0=sum_w 1=sum w*sx 2=sum w*sy 3=sum w*tx 4=sum w*ty
    //      5=sum w*tx*sx 6=sum w*tx*sy 7=sum w*ty*sx 8=sum w*ty*sy
    double acc[9] = {0,0,0,0,0,0,0,0,0};

    #pragma unroll
    for (int pass = 0; pass < PASSES; ++pass) {
        const float wf[4]  = {wv[pass].x, wv[pass].y, wv[pass].z, wv[pass].w};
        const float sxf[4] = {s0[pass].x, s0[pass].z, s1[pass].x, s1[pass].z};
        const float syf[4] = {s0[pass].y, s0[pass].w, s1[pass].y, s1[pass].w};
        const float txf[4] = {t0[pass].x, t0[pass].z, t1[pass].x, t1[pass].z};
        const float tyf[4] = {t0[pass].y, t0[pass].w, t1[pass].y, t1[pass].w};

        #pragma unroll
        for (int j = 0; j < 4; ++j) {
            const double w  = (double)wf[j];
            const double sx = (double)sxf[j], sy = (double)syf[j];
            const double tx = (double)txf[j], ty = (double)tyf[j];
            acc[0] += w;
            acc[1] = fma(w, sx, acc[1]);
            acc[2] = fma(w, sy, acc[2]);
            acc[3] = fma(w, tx, acc[3]);
            acc[4] = fma(w, ty, acc[4]);
            const double wt0 = w * tx, wt1 = w * ty;
            acc[5] = fma(wt0, sx, acc[5]);
            acc[6] = fma(wt0, sy, acc[6]);
            acc[7] = fma(wt1, sx, acc[7]);
            acc[8] = fma(wt1, sy, acc[8]);
        }
    }

    // wave64 butterfly reduce, then cross-wave via LDS (8 waves).
    #pragma unroll
    for (int k = 0; k < 9; ++k) acc[k] = wredd(acc[k]);

    __shared__ double red[TPB / 64][9];
    const int lane = tid & 63, wave = tid >> 6;
    if (lane == 0) {
        #pragma unroll
        for (int k = 0; k < 9; ++k) red[wave][k] = acc[k];
    }
    __syncthreads();

    if (tid == 0) {
        double s[9];
        #pragma unroll
        for (int k = 0; k < 9; ++k) {
            double v = red[0][k];
            #pragma unroll
            for (int wv2 = 1; wv2 < TPB / 64; ++wv2) v += red[wv2][k];
            s[k] = v;
        }

        const double w   = s[0] + EPSV;
        const double inv = 1.0 / w;
        const double scx = s[1] * inv, scy = s[2] * inv;   // src centroid (z=0)
        const double tcx = s[3] * inv, tcy = s[4] * inv;   // tgt centroid (z=0)

        // A_ij = sum w*t_i*s_j - (sum w*t_i)(sum w*s_j)/w  (scale-invariant)
        const double a00 = s[5] - s[3] * s[1] * inv;
        const double a01 = s[6] - s[3] * s[2] * inv;
        const double a10 = s[7] - s[4] * s[1] * inv;
        const double a11 = s[8] - s[4] * s[2] * inv;

        const double p = 0.5 * (a00 + a11);   // rotation part:   p*I + q*J
        const double q = 0.5 * (a10 - a01);
        const double r = 0.5 * (a00 - a11);   // reflection part: r*K + t*L
        const double t = 0.5 * (a01 + a10);

        const double rot2 = p * p + q * q;
        const double ref2 = r * r + t * t;    // det A = rot2 - ref2

        double R00, R01, R10, R11, Rzz;
        if (rot2 >= ref2) {                   // det(A) >= 0: closest rotation
            const double n = rsqrt(fmax(rot2, 1e-300));
            R00 =  p * n; R01 = -q * n;
            R10 =  q * n; R11 =  p * n;
            Rzz = 1.0;
        } else {                              // det(A) < 0: closest reflection
            const double n = rsqrt(fmax(ref2, 1e-300));
            R00 =  r * n; R01 =  t * n;
            R10 =  t * n; R11 = -r * n;
            Rzz = -1.0;
        }

        // t1 = src_c - R^T tgt_c ; t2 = -R t1   (z components exactly 0)
        const double t1x = scx - (R00 * tcx + R10 * tcy);
        const double t1y = scy - (R01 * tcx + R11 * tcy);
        const double t2x = -(R00 * t1x + R01 * t1y);
        const double t2y = -(R10 * t1x + R11 * t1y);

        float* Ro = out + (size_t)b * 9;
        Ro[0] = (float)R00; Ro[1] = (float)R01; Ro[2] = 0.0f;
        Ro[3] = (float)R10; Ro[4] = (float)R11; Ro[5] = 0.0f;
        Ro[6] = 0.0f;       Ro[7] = 0.0f;       Ro[8] = (float)Rzz;

        float* To = out + (size_t)BATCH * 9 + (size_t)b * 3;
        To[0] = (float)t2x; To[1] = (float)t2y; To[2] = 0.0f;
    }
}

extern "C" void kernel_launch(void* const* d_in, const int* in_sizes, int n_in,
                              void* d_out, int out_size, void* d_ws, size_t ws_size,
                              hipStream_t stream) {
    const float* src = (const float*)d_in[0];
    const float* tgt = (const float*)d_in[1];
    const float* wts = (const float*)d_in[2];
    float* out = (float*)d_out;
    procrustes_kernel<<<BATCH, TPB, 0, stream>>>(src, tgt, wts, out);
}

// Round 2
// 102.098 us; speedup vs baseline: 1.0159x; 1.0159x over previous
//
#include <hip/hip_runtime.h>

// Weighted 2D Procrustes (Kabsch) with z-padding == closed-form 2x2 polar factor.
// B=1024 batches, N=4096 points. Output: R [B,3,3] then t [B,3,1], fp32.
//
// R7: fp32 inner accumulation. R6 post-mortem: occupancy change was neutral;
// arithmetic says the fp64 inner loop (~230 quarter-rate f64 ops/thread ~ 8 us
// of VALU across the chip) was serializing with the 12.7-us memory stream ->
// 19.7 us kernel. Inner 16-term accumulation now fp32 (full-rate FMA, no cvt);
// per-thread partials converted to f64 ONCE, cross-lane butterfly + scalar
// tail stay f64. Summation order remains fixed -> replay-deterministic.
// Accuracy: per-thread f32 partial err ~6e-7, combined in f64 -> det err
// ~1e-3 vs det sigma ~2e3; sign-flip risk negligible (old f32 failure was
// sequential-4096 accumulation + nondeterministic combine order, 100x worse).
//
// Geometry: 512 thr/block (R6), 10 hoisted float4 loads (160 B/thread).

constexpr int BATCH = 1024;
constexpr int NPTS  = 4096;
constexpr int TPB   = 512;               // 8 waves/block
constexpr int PASSES = NPTS / (TPB * 4); // = 2
constexpr double EPSV = 1e-4;

__device__ __forceinline__ double wredd(double v) {
    #pragma unroll
    for (int off = 1; off < 64; off <<= 1) v += __shfl_xor(v, off, 64);
    return v;
}

__global__ __launch_bounds__(TPB) void procrustes_kernel(
    const float* __restrict__ src, const float* __restrict__ tgt,
    const float* __restrict__ wts, float* __restrict__ out)
{
    const int b   = blockIdx.x;
    const int tid = threadIdx.x;
    const float* sb = src + (size_t)b * (NPTS * 2);
    const float* tb = tgt + (size_t)b * (NPTS * 2);
    const float* wb = wts + (size_t)b * NPTS;

    // ---- issue ALL loads first (10 x float4 = 160 B/thread, coalesced) ----
    float4 wv[PASSES], s0[PASSES], s1[PASSES], t0[PASSES], t1[PASSES];
    #pragma unroll
    for (int pass = 0; pass < PASSES; ++pass) {
        const int i = tid * 4 + pass * (TPB * 4);
        wv[pass] = *reinterpret_cast<const float4*>(wb + i);
        s0[pass] = *reinterpret_cast<const float4*>(sb + 2 * i);
        s1[pass] = *reinterpret_cast<const float4*>(sb + 2 * i + 4);
        t0[pass] = *reinterpret_cast<const float4*>(tb + 2 * i);
        t1[pass] = *reinterpret_cast<const float4*>(tb + 2 * i + 4);
    }

    // acc: 0=sum_w 1=sum w*sx 2=sum w*sy 3=sum w*tx 4=sum w*ty
    //      5=sum w*tx*sx 6=sum w*tx*sy 7=sum w*ty*sx 8=sum w*ty*sy
    // fp32 per-thread partials (16 fixed-order terms each), f64 from there on.
    float accf[9] = {0,0,0,0,0,0,0,0,0};

    #pragma unroll
    for (int pass = 0; pass < PASSES; ++pass) {
        const float wf[4]  = {wv[pass].x, wv[pass].y, wv[pass].z, wv[pass].w};
        const float sxf[4] = {s0[pass].x, s0[pass].z, s1[pass].x, s1[pass].z};
        const float syf[4] = {s0[pass].y, s0[pass].w, s1[pass].y, s1[pass].w};
        const float txf[4] = {t0[pass].x, t0[pass].z, t1[pass].x, t1[pass].z};
        const float tyf[4] = {t0[pass].y, t0[pass].w, t1[pass].y, t1[pass].w};

        #pragma unroll
        for (int j = 0; j < 4; ++j) {
            const float w  = wf[j];
            const float sx = sxf[j], sy = syf[j];
            const float tx = txf[j], ty = tyf[j];
            accf[0] += w;
            accf[1] = fmaf(w, sx, accf[1]);
            accf[2] = fmaf(w, sy, accf[2]);
            accf[3] = fmaf(w, tx, accf[3]);
            accf[4] = fmaf(w, ty, accf[4]);
            const float wt0 = w * tx, wt1 = w * ty;
            accf[5] = fmaf(wt0, sx, accf[5]);
            accf[6] = fmaf(wt0, sy, accf[6]);
            accf[7] = fmaf(wt1, sx, accf[7]);
            accf[8] = fmaf(wt1, sy, accf[8]);
        }
    }

    double acc[9];
    #pragma unroll
    for (int k = 0; k < 9; ++k) acc[k] = (double)accf[k];

    // wave64 butterfly reduce (f64, pairwise-tree = deterministic + accurate),
    // then cross-wave via LDS (8 waves).
    #pragma unroll
    for (int k = 0; k < 9; ++k) acc[k] = wredd(acc[k]);

    __shared__ double red[TPB / 64][9];
    const int lane = tid & 63, wave = tid >> 6;
    if (lane == 0) {
        #pragma unroll
        for (int k = 0; k < 9; ++k) red[wave][k] = acc[k];
    }
    __syncthreads();

    if (tid == 0) {
        double s[9];
        #pragma unroll
        for (int k = 0; k < 9; ++k) {
            double v = red[0][k];
            #pragma unroll
            for (int wv2 = 1; wv2 < TPB / 64; ++wv2) v += red[wv2][k];
            s[k] = v;
        }

        const double w   = s[0] + EPSV;
        const double inv = 1.0 / w;
        const double scx = s[1] * inv, scy = s[2] * inv;   // src centroid (z=0)
        const double tcx = s[3] * inv, tcy = s[4] * inv;   // tgt centroid (z=0)

        // A_ij = sum w*t_i*s_j - (sum w*t_i)(sum w*s_j)/w  (scale-invariant)
        const double a00 = s[5] - s[3] * s[1] * inv;
        const double a01 = s[6] - s[3] * s[2] * inv;
        const double a10 = s[7] - s[4] * s[1] * inv;
        const double a11 = s[8] - s[4] * s[2] * inv;

        const double p = 0.5 * (a00 + a11);   // rotation part:   p*I + q*J
        const double q = 0.5 * (a10 - a01);
        const double r = 0.5 * (a00 - a11);   // reflection part: r*K + t*L
        const double t = 0.5 * (a01 + a10);

        const double rot2 = p * p + q * q;
        const double ref2 = r * r + t * t;    // det A = rot2 - ref2

        double R00, R01, R10, R11, Rzz;
        if (rot2 >= ref2) {                   // det(A) >= 0: closest rotation
            const double n = rsqrt(fmax(rot2, 1e-300));
            R00 =  p * n; R01 = -q * n;
            R10 =  q * n; R11 =  p * n;
            Rzz = 1.0;
        } else {                              // det(A) < 0: closest reflection
            const double n = rsqrt(fmax(ref2, 1e-300));
            R00 =  r * n; R01 =  t * n;
            R10 =  t * n; R11 = -r * n;
            Rzz = -1.0;
        }

        // t1 = src_c - R^T tgt_c ; t2 = -R t1   (z components exactly 0)
        const double t1x = scx - (R00 * tcx + R10 * tcy);
        const double t1y = scy - (R01 * tcx + R11 * tcy);
        const double t2x = -(R00 * t1x + R01 * t1y);
        const double t2y = -(R10 * t1x + R11 * t1y);

        float* Ro = out + (size_t)b * 9;
        Ro[0] = (float)R00; Ro[1] = (float)R01; Ro[2] = 0.0f;
        Ro[3] = (float)R10; Ro[4] = (float)R11; Ro[5] = 0.0f;
        Ro[6] = 0.0f;       Ro[7] = 0.0f;       Ro[8] = (float)Rzz;

        float* To = out + (size_t)BATCH * 9 + (size_t)b * 3;
        To[0] = (float)t2x; To[1] = (float)t2y; To[2] = 0.0f;
    }
}

extern "C" void kernel_launch(void* const* d_in, const int* in_sizes, int n_in,
                              void* d_out, int out_size, void* d_ws, size_t ws_size,
                              hipStream_t stream) {
    const float* src = (const float*)d_in[0];
    const float* tgt = (const float*)d_in[1];
    const float* wts = (const float*)d_in[2];
    float* out = (float*)d_out;
    procrustes_kernel<<<BATCH, TPB, 0, stream>>>(src, tgt, wts, out);
}

// Round 3
// 100.641 us; speedup vs baseline: 1.0306x; 1.0145x over previous
//
#include <hip/hip_runtime.h>

// Weighted 2D Procrustes (Kabsch) with z-padding == closed-form 2x2 polar factor.
// B=1024 batches, N=4096 points. Output: R [B,3,3] then t [B,3,1], fp32.
//
// R8: replace the f64 shuffle butterfly with a direct LDS reduction.
// Post-mortem R6/R7: total = fills(82.6us, harness-fixed) + kernel(19.5us),
// kernel insensitive to occupancy AND inner precision -> residual ~7us over
// the 12.7us memory floor sits in the untouched reduction. wredd was
// 9 f64 x 6 levels x 2 ds_bpermute = 108 LDS-pipe instrs/wave (~650 cyc),
// phase-synchronized across all resident blocks (they start together), so
// it did NOT overlap with memory. New scheme: 9 f32 partials -> LDS
// ([512][9], 9 odd => bank-permutation, <=2-way conflicts = free), 288
// threads each fold 16 interleaved rows (r = c + 32*i) in f64, 9 threads
// fold 32 chunks. ~110 LDS wave-instrs vs ~864. Fixed-order f64 combine
// preserved -> replay-deterministic, same accuracy class as R7.
//
// Geometry: 512 thr/block, 10 hoisted float4 loads (160 B/thread).

constexpr int BATCH = 1024;
constexpr int NPTS  = 4096;
constexpr int TPB   = 512;               // 8 waves/block
constexpr int PASSES = NPTS / (TPB * 4); // = 2
constexpr double EPSV = 1e-4;

__global__ __launch_bounds__(TPB) void procrustes_kernel(
    const float* __restrict__ src, const float* __restrict__ tgt,
    const float* __restrict__ wts, float* __restrict__ out)
{
    const int b   = blockIdx.x;
    const int tid = threadIdx.x;
    const float* sb = src + (size_t)b * (NPTS * 2);
    const float* tb = tgt + (size_t)b * (NPTS * 2);
    const float* wb = wts + (size_t)b * NPTS;

    // ---- issue ALL loads first (10 x float4 = 160 B/thread, coalesced) ----
    float4 wv[PASSES], s0[PASSES], s1[PASSES], t0[PASSES], t1[PASSES];
    #pragma unroll
    for (int pass = 0; pass < PASSES; ++pass) {
        const int i = tid * 4 + pass * (TPB * 4);
        wv[pass] = *reinterpret_cast<const float4*>(wb + i);
        s0[pass] = *reinterpret_cast<const float4*>(sb + 2 * i);
        s1[pass] = *reinterpret_cast<const float4*>(sb + 2 * i + 4);
        t0[pass] = *reinterpret_cast<const float4*>(tb + 2 * i);
        t1[pass] = *reinterpret_cast<const float4*>(tb + 2 * i + 4);
    }

    // acc: 0=sum_w 1=sum w*sx 2=sum w*sy 3=sum w*tx 4=sum w*ty
    //      5=sum w*tx*sx 6=sum w*tx*sy 7=sum w*ty*sx 8=sum w*ty*sy
    // fp32 per-thread partials (16 fixed-order terms each), f64 from there on.
    float accf[9] = {0,0,0,0,0,0,0,0,0};

    #pragma unroll
    for (int pass = 0; pass < PASSES; ++pass) {
        const float wf[4]  = {wv[pass].x, wv[pass].y, wv[pass].z, wv[pass].w};
        const float sxf[4] = {s0[pass].x, s0[pass].z, s1[pass].x, s1[pass].z};
        const float syf[4] = {s0[pass].y, s0[pass].w, s1[pass].y, s1[pass].w};
        const float txf[4] = {t0[pass].x, t0[pass].z, t1[pass].x, t1[pass].z};
        const float tyf[4] = {t0[pass].y, t0[pass].w, t1[pass].y, t1[pass].w};

        #pragma unroll
        for (int j = 0; j < 4; ++j) {
            const float w  = wf[j];
            const float sx = sxf[j], sy = syf[j];
            const float tx = txf[j], ty = tyf[j];
            accf[0] += w;
            accf[1] = fmaf(w, sx, accf[1]);
            accf[2] = fmaf(w, sy, accf[2]);
            accf[3] = fmaf(w, tx, accf[3]);
            accf[4] = fmaf(w, ty, accf[4]);
            const float wt0 = w * tx, wt1 = w * ty;
            accf[5] = fmaf(wt0, sx, accf[5]);
            accf[6] = fmaf(wt0, sy, accf[6]);
            accf[7] = fmaf(wt1, sx, accf[7]);
            accf[8] = fmaf(wt1, sy, accf[8]);
        }
    }

    // ---- direct LDS reduction (no bpermute butterfly) ----
    // part[512][9] f32: writes are b128/b32 at word-stride 9 (odd) -> bank
    // permutation across lanes, conflict-free-ish (<=2-way).
    __shared__ float  part[TPB][9];     // 18432 B
    __shared__ double p2[9][32];        //  2304 B
    __shared__ double sfin[9];

    #pragma unroll
    for (int k = 0; k < 9; ++k) part[tid][k] = accf[k];
    __syncthreads();

    // 288 threads: thread (k = t>>5, c = t&31) folds rows r = c + 32*i.
    // Read banks: (9*(c+32i) + k) % 32 = (9c + k) % 32 -> permutation in c,
    // +k gives at most 2-way aliasing (free per m136).
    if (tid < 288) {
        const int k = tid >> 5, c = tid & 31;
        double v = 0.0;
        #pragma unroll
        for (int i = 0; i < 16; ++i) v += (double)part[c + 32 * i][k];
        p2[k][c] = v;
    }
    __syncthreads();

    // 9 threads fold 32 chunks each (fixed order, f64).
    if (tid < 9) {
        double v = 0.0;
        #pragma unroll
        for (int c = 0; c < 32; ++c) v += p2[tid][c];
        sfin[tid] = v;
    }
    __syncthreads();

    if (tid == 0) {
        double s[9];
        #pragma unroll
        for (int k = 0; k < 9; ++k) s[k] = sfin[k];

        const double w   = s[0] + EPSV;
        const double inv = 1.0 / w;
        const double scx = s[1] * inv, scy = s[2] * inv;   // src centroid (z=0)
        const double tcx = s[3] * inv, tcy = s[4] * inv;   // tgt centroid (z=0)

        // A_ij = sum w*t_i*s_j - (sum w*t_i)(sum w*s_j)/w  (scale-invariant)
        const double a00 = s[5] - s[3] * s[1] * inv;
        const double a01 = s[6] - s[3] * s[2] * inv;
        const double a10 = s[7] - s[4] * s[1] * inv;
        const double a11 = s[8] - s[4] * s[2] * inv;

        const double p = 0.5 * (a00 + a11);   // rotation part:   p*I + q*J
        const double q = 0.5 * (a10 - a01);
        const double r = 0.5 * (a00 - a11);   // reflection part: r*K + t*L
        const double t = 0.5 * (a01 + a10);

        const double rot2 = p * p + q * q;
        const double ref2 = r * r + t * t;    // det A = rot2 - ref2

        double R00, R01, R10, R11, Rzz;
        if (rot2 >= ref2) {                   // det(A) >= 0: closest rotation
            const double n = rsqrt(fmax(rot2, 1e-300));
            R00 =  p * n; R01 = -q * n;
            R10 =  q * n; R11 =  p * n;
            Rzz = 1.0;
        } else {                              // det(A) < 0: closest reflection
            const double n = rsqrt(fmax(ref2, 1e-300));
            R00 =  r * n; R01 =  t * n;
            R10 =  t * n; R11 = -r * n;
            Rzz = -1.0;
        }

        // t1 = src_c - R^T tgt_c ; t2 = -R t1   (z components exactly 0)
        const double t1x = scx - (R00 * tcx + R10 * tcy);
        const double t1y = scy - (R01 * tcx + R11 * tcy);
        const double t2x = -(R00 * t1x + R01 * t1y);
        const double t2y = -(R10 * t1x + R11 * t1y);

        float* Ro = out + (size_t)b * 9;
        Ro[0] = (float)R00; Ro[1] = (float)R01; Ro[2] = 0.0f;
        Ro[3] = (float)R10; Ro[4] = (float)R11; Ro[5] = 0.0f;
        Ro[6] = 0.0f;       Ro[7] = 0.0f;       Ro[8] = (float)Rzz;

        float* To = out + (size_t)BATCH * 9 + (size_t)b * 3;
        To[0] = (float)t2x; To[1] = (float)t2y; To[2] = 0.0f;
    }
}

extern "C" void kernel_launch(void* const* d_in, const int* in_sizes, int n_in,
                              void* d_out, int out_size, void* d_ws, size_t ws_size,
                              hipStream_t stream) {
    const float* src = (const float*)d_in[0];
    const float* tgt = (const float*)d_in[1];
    const float* wts = (const float*)d_in[2];
    float* out = (float*)d_out;
    procrustes_kernel<<<BATCH, TPB, 0, stream>>>(src, tgt, wts, out);
}

// Round 4
// 100.224 us; speedup vs baseline: 1.0349x; 1.0042x over previous
//
#include <hip/hip_runtime.h>

// Weighted 2D Procrustes (Kabsch) with z-padding == closed-form 2x2 polar factor.
// B=1024 batches, N=4096 points. Output: R [B,3,3] then t [B,3,1], fp32.
//
// R9: attack the phase-synchronized post-stream tail (~2.5us of kernel's
// 16.4us vs the 12.7us memory floor; fills = 84us harness-fixed).
//  (a) Stage-1 reduction moves from LDS to VALU: classic DPP cross-lane sum
//      (row_shr:1/2/4/8 + row_bcast:15/31 -> full wave64 sum in lane 63).
//      9 accs x 6 stages = 108 VALU instrs; LDS shrinks to 8x9 f32 + f64 fold
//      (~12 wave-LDS instrs/block vs ~110 in R8) -> per-CU LDS pipe no longer
//      serializes the 4 co-resident blocks' endgame.
//  (b) Inner loop packed: float2 ext-vectors + __builtin_elementwise_fma ->
//      v_pk_fma_f32 (gfx90a+). ~6-8 VALU/point vs 11 -> halves exposed tail
//      compute. Worst case lowers to 2x v_fma_f32 = current code.
// Numerics: per-thread f32 partials (fixed order), f32 DPP tree per wave
// (fixed order), f64 cross-wave + tail. Deterministic across replays.
// absmax has been reference-quantization-bound (2^-9) since R5 -> headroom.

constexpr int BATCH = 1024;
constexpr int NPTS  = 4096;
constexpr int TPB   = 512;               // 8 waves/block
constexpr int PASSES = NPTS / (TPB * 4); // = 2
constexpr double EPSV = 1e-4;

typedef float v2f __attribute__((ext_vector_type(2)));

// Full-wave64 f32 sum via DPP; result valid in lane 63 only.
// old=0 + bound_ctrl: invalid-source lanes contribute 0 (harmless for sum).
#define DPP_STEP(x, ctrl)                                                     \
    (x) += __uint_as_float(__builtin_amdgcn_update_dpp(                        \
        0, (int)__float_as_uint(x), (ctrl), 0xf, 0xf, true))

__device__ __forceinline__ float wave_sum_dpp(float x) {
    DPP_STEP(x, 0x111);  // row_shr:1
    DPP_STEP(x, 0x112);  // row_shr:2
    DPP_STEP(x, 0x114);  // row_shr:4
    DPP_STEP(x, 0x118);  // row_shr:8  -> lane 16r+15 = row sum (tree)
    DPP_STEP(x, 0x142);  // row_bcast:15 -> lane31 = r0+r1, lane63 = r2+r3
    DPP_STEP(x, 0x143);  // row_bcast:31 -> lane63 = total
    return x;
}

__global__ __launch_bounds__(TPB) void procrustes_kernel(
    const float* __restrict__ src, const float* __restrict__ tgt,
    const float* __restrict__ wts, float* __restrict__ out)
{
    const int b   = blockIdx.x;
    const int tid = threadIdx.x;
    const float* sb = src + (size_t)b * (NPTS * 2);
    const float* tb = tgt + (size_t)b * (NPTS * 2);
    const float* wb = wts + (size_t)b * NPTS;

    // ---- issue ALL loads first (10 x float4 = 160 B/thread, coalesced) ----
    float4 wv[PASSES], s0[PASSES], s1[PASSES], t0[PASSES], t1[PASSES];
    #pragma unroll
    for (int pass = 0; pass < PASSES; ++pass) {
        const int i = tid * 4 + pass * (TPB * 4);
        wv[pass] = *reinterpret_cast<const float4*>(wb + i);
        s0[pass] = *reinterpret_cast<const float4*>(sb + 2 * i);
        s1[pass] = *reinterpret_cast<const float4*>(sb + 2 * i + 4);
        t0[pass] = *reinterpret_cast<const float4*>(tb + 2 * i);
        t1[pass] = *reinterpret_cast<const float4*>(tb + 2 * i + 4);
    }

    // Packed accumulators (v_pk_fma_f32 path):
    //   accS = (sum w*sx, sum w*sy)      accT = (sum w*tx, sum w*ty)
    //   accX = (sum w*tx*sx, w*tx*sy)    accY = (sum w*ty*sx, w*ty*sy)
    //   accW = sum w
    v2f accS = {0.f, 0.f}, accT = {0.f, 0.f}, accX = {0.f, 0.f}, accY = {0.f, 0.f};
    float accW = 0.f;

    #pragma unroll
    for (int pass = 0; pass < PASSES; ++pass) {
        const float wk[4] = {wv[pass].x, wv[pass].y, wv[pass].z, wv[pass].w};
        const v2f sp[4] = {{s0[pass].x, s0[pass].y}, {s0[pass].z, s0[pass].w},
                           {s1[pass].x, s1[pass].y}, {s1[pass].z, s1[pass].w}};
        const v2f tp[4] = {{t0[pass].x, t0[pass].y}, {t0[pass].z, t0[pass].w},
                           {t1[pass].x, t1[pass].y}, {t1[pass].z, t1[pass].w}};

        #pragma unroll
        for (int j = 0; j < 4; ++j) {
            const float w = wk[j];
            const v2f w2  = {w, w};
            const v2f wt  = w2 * tp[j];           // (w*tx, w*ty)  pk_mul
            accW += w;
            accT += wt;                           // pk_add
            accS = __builtin_elementwise_fma(w2, sp[j], accS);
            const v2f wtx = {wt.x, wt.x};
            accX = __builtin_elementwise_fma(wtx, sp[j], accX);
            const v2f wty = {wt.y, wt.y};
            accY = __builtin_elementwise_fma(wty, sp[j], accY);
        }
    }

    // acc order matches tail: 0=W 1=wsx 2=wsy 3=wtx 4=wty 5=wtxsx 6=wtxsy
    //                         7=wtysx 8=wtysy
    float accf[9] = {accW, accS.x, accS.y, accT.x, accT.y,
                     accX.x, accX.y, accY.x, accY.y};

    // ---- stage 1: VALU (DPP) wave reduction, total lands in lane 63 ----
    #pragma unroll
    for (int k = 0; k < 9; ++k) accf[k] = wave_sum_dpp(accf[k]);

    __shared__ float  red[TPB / 64][9];   // 288 B
    __shared__ double sfin[9];
    const int lane = tid & 63, wave = tid >> 6;
    if (lane == 63) {
        #pragma unroll
        for (int k = 0; k < 9; ++k) red[wave][k] = accf[k];
    }
    __syncthreads();

    // ---- stage 2: 9 threads fold 8 wave-sums in f64, fixed order ----
    if (tid < 9) {
        double v = 0.0;
        #pragma unroll
        for (int wv2 = 0; wv2 < TPB / 64; ++wv2) v += (double)red[wv2][tid];
        sfin[tid] = v;
    }
    __syncthreads();

    if (tid == 0) {
        double s[9];
        #pragma unroll
        for (int k = 0; k < 9; ++k) s[k] = sfin[k];

        const double w   = s[0] + EPSV;
        const double inv = 1.0 / w;
        const double scx = s[1] * inv, scy = s[2] * inv;   // src centroid (z=0)
        const double tcx = s[3] * inv, tcy = s[4] * inv;   // tgt centroid (z=0)

        // A_ij = sum w*t_i*s_j - (sum w*t_i)(sum w*s_j)/w  (scale-invariant)
        const double a00 = s[5] - s[3] * s[1] * inv;
        const double a01 = s[6] - s[3] * s[2] * inv;
        const double a10 = s[7] - s[4] * s[1] * inv;
        const double a11 = s[8] - s[4] * s[2] * inv;

        const double p = 0.5 * (a00 + a11);   // rotation part:   p*I + q*J
        const double q = 0.5 * (a10 - a01);
        const double r = 0.5 * (a00 - a11);   // reflection part: r*K + t*L
        const double t = 0.5 * (a01 + a10);

        const double rot2 = p * p + q * q;
        const double ref2 = r * r + t * t;    // det A = rot2 - ref2

        double R00, R01, R10, R11, Rzz;
        if (rot2 >= ref2) {                   // det(A) >= 0: closest rotation
            const double n = rsqrt(fmax(rot2, 1e-300));
            R00 =  p * n; R01 = -q * n;
            R10 =  q * n; R11 =  p * n;
            Rzz = 1.0;
        } else {                              // det(A) < 0: closest reflection
            const double n = rsqrt(fmax(ref2, 1e-300));
            R00 =  r * n; R01 =  t * n;
            R10 =  t * n; R11 = -r * n;
            Rzz = -1.0;
        }

        // t1 = src_c - R^T tgt_c ; t2 = -R t1   (z components exactly 0)
        const double t1x = scx - (R00 * tcx + R10 * tcy);
        const double t1y = scy - (R01 * tcx + R11 * tcy);
        const double t2x = -(R00 * t1x + R01 * t1y);
        const double t2y = -(R10 * t1x + R11 * t1y);

        float* Ro = out + (size_t)b * 9;
        Ro[0] = (float)R00; Ro[1] = (float)R01; Ro[2] = 0.0f;
        Ro[3] = (float)R10; Ro[4] = (float)R11; Ro[5] = 0.0f;
        Ro[6] = 0.0f;       Ro[7] = 0.0f;       Ro[8] = (float)Rzz;

        float* To = out + (size_t)BATCH * 9 + (size_t)b * 3;
        To[0] = (float)t2x; To[1] = (float)t2y; To[2] = 0.0f;
    }
}

extern "C" void kernel_launch(void* const* d_in, const int* in_sizes, int n_in,
                              void* d_out, int out_size, void* d_ws, size_t ws_size,
                              hipStream_t stream) {
    const float* src = (const float*)d_in[0];
    const float* tgt = (const float*)d_in[1];
    const float* wts = (const float*)d_in[2];
    float* out = (float*)d_out;
    procrustes_kernel<<<BATCH, TPB, 0, stream>>>(src, tgt, wts, out);
}